// Round 1
// baseline (218.771 us; speedup 1.0000x reference)
//
#include <hip/hip_runtime.h>
#include <cstddef>

#define N_TOT   8
#define R_TOT   2048
#define NR_TOT  (N_TOT*R_TOT)      // 16384 points
#define KK      16
#define DD      3
#define CL      64                  // C_LIFT
#define CM      128                 // C_MID == C_OUT
#define EPSV    1e-5f
#define CNTF    262144.0f           // N*R*K

__device__ __forceinline__ float elu_f(float x){
    return x > 0.f ? x : (__expf(x) - 1.f);
}

// ---------------- Pass 1: global BN stats (sum, sumsq per d) ----------------
__global__ __launch_bounds__(256) void xconv_stats(
    const float* __restrict__ p, const float* __restrict__ P, float* __restrict__ ws)
{
    float s1[3] = {0.f,0.f,0.f}, s2[3] = {0.f,0.f,0.f};
    const int total = NR_TOT * KK;
    for (int idx = blockIdx.x*256 + threadIdx.x; idx < total; idx += gridDim.x*256){
        int nr = idx >> 4;
        #pragma unroll
        for (int d = 0; d < 3; d++){
            float v = P[idx*3 + d] - p[nr*3 + d];
            s1[d] += v;
            s2[d] += v*v;
        }
    }
    // wave (64-lane) butterfly reduce
    #pragma unroll
    for (int off = 32; off > 0; off >>= 1){
        #pragma unroll
        for (int d = 0; d < 3; d++){
            s1[d] += __shfl_down(s1[d], off, 64);
            s2[d] += __shfl_down(s2[d], off, 64);
        }
    }
    __shared__ float red[4][6];
    int wave = threadIdx.x >> 6, lane = threadIdx.x & 63;
    if (lane == 0){
        #pragma unroll
        for (int d = 0; d < 3; d++){ red[wave][d] = s1[d]; red[wave][3+d] = s2[d]; }
    }
    __syncthreads();
    if (threadIdx.x < 6){
        float a = red[0][threadIdx.x] + red[1][threadIdx.x]
                + red[2][threadIdx.x] + red[3][threadIdx.x];
        atomicAdd(&ws[threadIdx.x], a);
    }
}

// ---------------- Pass 2: finalize scale/shift ----------------
__global__ void xconv_finalize(const float* __restrict__ gamma,
                               const float* __restrict__ beta,
                               float* __restrict__ ws)
{
    int d = threadIdx.x;
    if (d < 3){
        float mean  = ws[d]   / CNTF;
        float var   = ws[3+d] / CNTF - mean*mean;
        float scale = gamma[d] * rsqrtf(var + EPSV);
        ws[8+d]  = scale;                    // P_norm = P_local*scale + shift
        ws[11+d] = beta[d] - mean*scale;
    }
}

// ---------------- Pass 3: fused per-point kernel ----------------
// block = 128 threads = one point (n,r); thread t maps to channel c in epilogue
__global__ __launch_bounds__(128) void xconv_main(
    const float* __restrict__ p,   const float* __restrict__ P,
    const float* __restrict__ F,
    const float* __restrict__ w1,  const float* __restrict__ b1,
    const float* __restrict__ w2,  const float* __restrict__ b2,
    const float* __restrict__ midw,const float* __restrict__ midb,
    const float* __restrict__ mlpw,const float* __restrict__ mlpb,
    const float* __restrict__ endw,const float* __restrict__ endb,
    const float* __restrict__ ws,  float* __restrict__ out)
{
    __shared__ float sPn[KK][DD];       // P_norm  16x3
    __shared__ float sH1Q[CL][KK];      // h1 transposed [q][k]  64x16 (4 KB)
    __shared__ float sX0[KK*KK];        // pre-mlp X  (1 KB)
    __shared__ float sX [KK*KK];        // X (post elu) (1 KB)
    __shared__ float sFcat[KK][CM];     // F_cat [k][c]  (8 KB)

    const int t  = threadIdx.x;
    const int nr = blockIdx.x;

    float sc[3], sh[3];
    #pragma unroll
    for (int d = 0; d < 3; d++){ sc[d] = ws[8+d]; sh[d] = ws[11+d]; }

    // --- Phase A: P_norm (48 values) ---
    if (t < 48){
        int k = t / 3, d = t - k*3;
        float pl = P[((size_t)nr*KK + k)*3 + d] - p[(size_t)nr*3 + d];
        sPn[k][d] = pl*sc[d] + sh[d];
    }
    // --- Load F into right half of F_cat (1024 floats, float4-coalesced) ---
    {
        const float4* Fp = (const float4*)(F + (size_t)nr * (KK*CL));
        #pragma unroll
        for (int i = 0; i < 2; i++){
            int m = t + i*128;                 // 0..255 float4s
            float4 v = Fp[m];
            int k = m >> 4, c4 = m & 15;
            *((float4*)&sFcat[k][CL + c4*4]) = v;
        }
    }
    __syncthreads();

    // --- Phase B: h1 = elu(P_norm @ w1 + b1), stored transposed [q][k] ---
    {
        int k = t >> 3, qb = (t & 7) * 8;
        float pn0 = sPn[k][0], pn1 = sPn[k][1], pn2 = sPn[k][2];
        #pragma unroll
        for (int i = 0; i < 8; i++){
            int q = qb + i;
            float h = b1[q] + pn0*w1[q] + pn1*w1[CL + q] + pn2*w1[2*CL + q];
            sH1Q[q][k] = elu_f(h);
        }
    }
    // --- Phase D0: X0 = P_norm @ midw + midb  (16x16) ---
    #pragma unroll
    for (int i = 0; i < 2; i++){
        int e = t + i*128;
        int k = e >> 4, j = e & 15;
        float x = midb[j] + sPn[k][0]*midw[j] + sPn[k][1]*midw[16 + j]
                + sPn[k][2]*midw[32 + j];
        sX0[e] = x;
    }
    __syncthreads();

    // --- Phase C: F_lift = elu(h1 @ w2 + b2) -> left half of F_cat ---
    // thread: fixed c = t&63, covers 8 k's (kb..kb+7)
    {
        int c = t & 63, kb = (t >> 6) * 8;
        float acc[8];
        float bb = b2[c];
        #pragma unroll
        for (int i = 0; i < 8; i++) acc[i] = bb;
        #pragma unroll 8
        for (int q = 0; q < CL; q++){
            float w = w2[q*CL + c];                         // coalesced, L1-hot
            const float4* hp = (const float4*)&sH1Q[q][kb]; // LDS broadcast
            float4 a0 = hp[0], a1 = hp[1];
            acc[0] += a0.x*w; acc[1] += a0.y*w; acc[2] += a0.z*w; acc[3] += a0.w*w;
            acc[4] += a1.x*w; acc[5] += a1.y*w; acc[6] += a1.z*w; acc[7] += a1.w*w;
        }
        #pragma unroll
        for (int i = 0; i < 8; i++)
            sFcat[kb + i][c] = elu_f(acc[i]);
    }
    // --- Phase D1: X = elu(X0 @ mlpw + mlpb) ---
    #pragma unroll
    for (int i = 0; i < 2; i++){
        int e = t + i*128;
        int k = e >> 4, j = e & 15;
        float x = mlpb[j];
        #pragma unroll
        for (int m = 0; m < 16; m++) x += sX0[k*16 + m] * mlpw[m*16 + j];
        sX[e] = elu_f(x);
    }
    __syncthreads();

    // --- Phase E: G[c][j] = sum_k endw[c][k] * X[k][j] ---
    // --- Phase F: F_p[c] = endb[c] + sum_j G[c][j]*F_cat[j][c] ---
    {
        int c = t;
        float ew[16];
        const float4* ewp = (const float4*)(endw + (size_t)c*16);  // per-lane 64B, coalesced
        #pragma unroll
        for (int i = 0; i < 4; i++){
            float4 v = ewp[i];
            ew[4*i] = v.x; ew[4*i+1] = v.y; ew[4*i+2] = v.z; ew[4*i+3] = v.w;
        }
        float G[16];
        #pragma unroll
        for (int j = 0; j < 16; j++) G[j] = 0.f;
        #pragma unroll
        for (int k = 0; k < 16; k++){
            const float4* xp = (const float4*)&sX[k*16];   // LDS broadcast
            float4 x0 = xp[0], x1 = xp[1], x2 = xp[2], x3 = xp[3];
            float w = ew[k];
            G[0]  += w*x0.x; G[1]  += w*x0.y; G[2]  += w*x0.z; G[3]  += w*x0.w;
            G[4]  += w*x1.x; G[5]  += w*x1.y; G[6]  += w*x1.z; G[7]  += w*x1.w;
            G[8]  += w*x2.x; G[9]  += w*x2.y; G[10] += w*x2.z; G[11] += w*x2.w;
            G[12] += w*x3.x; G[13] += w*x3.y; G[14] += w*x3.z; G[15] += w*x3.w;
        }
        float fp = endb[c];
        #pragma unroll
        for (int j = 0; j < 16; j++) fp += G[j] * sFcat[j][c];   // 2-way bank alias: free
        out[(size_t)nr*CM + c] = fp;
    }
}

extern "C" void kernel_launch(void* const* d_in, const int* in_sizes, int n_in,
                              void* d_out, int out_size, void* d_ws, size_t ws_size,
                              hipStream_t stream)
{
    const float* p     = (const float*)d_in[0];
    const float* P     = (const float*)d_in[1];
    const float* F     = (const float*)d_in[2];
    const float* gamma = (const float*)d_in[3];
    const float* beta  = (const float*)d_in[4];
    const float* w1    = (const float*)d_in[5];
    const float* b1    = (const float*)d_in[6];
    const float* w2    = (const float*)d_in[7];
    const float* b2    = (const float*)d_in[8];
    const float* midw  = (const float*)d_in[9];
    const float* midb  = (const float*)d_in[10];
    const float* mlpw  = (const float*)d_in[11];
    const float* mlpb  = (const float*)d_in[12];
    const float* endw  = (const float*)d_in[13];
    const float* endb  = (const float*)d_in[14];
    float* ws  = (float*)d_ws;
    float* out = (float*)d_out;

    hipMemsetAsync(d_ws, 0, 32, stream);                 // zero ws[0..7]
    xconv_stats   <<<256, 256, 0, stream>>>(p, P, ws);
    xconv_finalize<<<1,   64,  0, stream>>>(gamma, beta, ws);
    xconv_main    <<<NR_TOT, 128, 0, stream>>>(p, P, F, w1, b1, w2, b2,
                                               midw, midb, mlpw, mlpb,
                                               endw, endb, ws, out);
}

// Round 2
// 152.533 us; speedup vs baseline: 1.4342x; 1.4342x over previous
//
#include <hip/hip_runtime.h>
#include <cstddef>

#define N_TOT   8
#define R_TOT   2048
#define NR_TOT  (N_TOT*R_TOT)      // 16384 points
#define KK      16
#define CL      64
#define CM      128
#define EPSV    1e-5f
#define CNTF    262144.0f

typedef float  f32x4  __attribute__((ext_vector_type(4)));
typedef short  bf16x8 __attribute__((ext_vector_type(8)));

union FragU { bf16x8 f; unsigned u[4]; };

__device__ __forceinline__ float elu_f(float x){
    return x > 0.f ? x : (__expf(x) - 1.f);
}
__device__ __forceinline__ unsigned pk_bf16(float a, float b){   // RNE pack 2xbf16
    unsigned ua = __float_as_uint(a), ub = __float_as_uint(b);
    ua += 0x7fff + ((ua >> 16) & 1);
    ub += 0x7fff + ((ub >> 16) & 1);
    return (ua >> 16) | (ub & 0xffff0000u);
}
__device__ __forceinline__ float bf_lo(unsigned u){ return __uint_as_float(u << 16); }
__device__ __forceinline__ float bf_hi(unsigned u){ return __uint_as_float(u & 0xffff0000u); }

// split 4 floats -> (hi01, hi23, lo01, lo23); hi+lo == x to ~2^-17 rel
__device__ __forceinline__ void split4(const float* x, unsigned* o){
    unsigned h01 = pk_bf16(x[0], x[1]);
    unsigned h23 = pk_bf16(x[2], x[3]);
    float l0 = x[0] - bf_lo(h01), l1 = x[1] - bf_hi(h01);
    float l2 = x[2] - bf_lo(h23), l3 = x[3] - bf_hi(h23);
    o[0] = h01; o[1] = h23; o[2] = pk_bf16(l0, l1); o[3] = pk_bf16(l2, l3);
}

// ---------------- Pass 1: global BN stats (sum, sumsq per d) ----------------
__global__ __launch_bounds__(256) void xconv_stats(
    const float* __restrict__ p, const float* __restrict__ P, float* __restrict__ ws)
{
    float s1[3] = {0.f,0.f,0.f}, s2[3] = {0.f,0.f,0.f};
    const int total = NR_TOT * KK;
    for (int idx = blockIdx.x*256 + threadIdx.x; idx < total; idx += gridDim.x*256){
        int nr = idx >> 4;
        #pragma unroll
        for (int d = 0; d < 3; d++){
            float v = P[idx*3 + d] - p[nr*3 + d];
            s1[d] += v;
            s2[d] += v*v;
        }
    }
    #pragma unroll
    for (int off = 32; off > 0; off >>= 1){
        #pragma unroll
        for (int d = 0; d < 3; d++){
            s1[d] += __shfl_down(s1[d], off, 64);
            s2[d] += __shfl_down(s2[d], off, 64);
        }
    }
    __shared__ float red[4][6];
    int wave = threadIdx.x >> 6, lane = threadIdx.x & 63;
    if (lane == 0){
        #pragma unroll
        for (int d = 0; d < 3; d++){ red[wave][d] = s1[d]; red[wave][3+d] = s2[d]; }
    }
    __syncthreads();
    if (threadIdx.x < 6){
        float a = red[0][threadIdx.x] + red[1][threadIdx.x]
                + red[2][threadIdx.x] + red[3][threadIdx.x];
        atomicAdd(&ws[threadIdx.x], a);
    }
}

// ---------------- Pass 2: fused MFMA kernel ----------------
// 1024 blocks x 256 thr; each wave handles 4 points.
__global__ __launch_bounds__(256) void xconv_main(
    const float* __restrict__ p,   const float* __restrict__ P,
    const float* __restrict__ F,
    const float* __restrict__ gamma,const float* __restrict__ beta,
    const float* __restrict__ w1,  const float* __restrict__ b1,
    const float* __restrict__ w2,  const float* __restrict__ b2,
    const float* __restrict__ midw,const float* __restrict__ midb,
    const float* __restrict__ mlpw,const float* __restrict__ mlpb,
    const float* __restrict__ endw,const float* __restrict__ endb,
    const float* __restrict__ ws,  float* __restrict__ out)
{
    __shared__ float sEndw[128*20];            // row stride 20 floats (80 B)

    const int tid  = threadIdx.x;
    const int lane = tid & 63;
    const int lo16 = lane & 15;
    const int quad = lane >> 4;
    const int wave = tid >> 6;

    // ---- stage endw [c][k] into LDS (rows padded to 80 B) ----
    {
        const float4* ep = (const float4*)endw;          // 512 float4
        float4 v0 = ep[tid*2], v1 = ep[tid*2 + 1];
        int c = tid >> 1, k0 = (tid & 1) * 8;
        float* dst = &sEndw[c*20 + k0];
        *(float4*)dst = v0; *(float4*)(dst + 4) = v1;
    }
    __syncthreads();

    // ---- BN scale/shift (finalize fused; uniform per wave) ----
    float sc[3], sh[3];
    #pragma unroll
    for (int d = 0; d < 3; d++){
        float mean = ws[d] / CNTF;
        float var  = ws[3+d] / CNTF - mean*mean;
        float s    = gamma[d] * rsqrtf(var + EPSV);
        sc[d] = s; sh[d] = beta[d] - mean*s;
    }

    // ---- static weight registers ----
    // w1/b1 packed bf16: q = s*32 + quad*8 + j
    unsigned w1pk[2][8][2];
    #pragma unroll
    for (int s = 0; s < 2; s++)
        #pragma unroll
        for (int j = 0; j < 8; j++){
            int q = s*32 + quad*8 + j;
            w1pk[s][j][0] = pk_bf16(w1[q],        w1[64 + q]);
            w1pk[s][j][1] = pk_bf16(w1[128 + q],  b1[q]);
        }
    // w2 B-frags: tile b (cols b*16+lo16), K-step s, rows quad*8+jj
    FragU w2f[4][2];
    #pragma unroll
    for (int b = 0; b < 4; b++)
        #pragma unroll
        for (int s = 0; s < 2; s++)
            #pragma unroll
            for (int d = 0; d < 4; d++){
                int q0 = s*32 + quad*8 + d*2;
                int idx = q0*64 + b*16 + lo16;
                w2f[b][s].u[d] = pk_bf16(w2[idx], w2[idx + 64]);
            }
    // mlp A-frags (mlpw^T, hi/lo split, quad-dup)
    FragU mlpA[2];
    {
        float mw[4];
        #pragma unroll
        for (int r = 0; r < 4; r++) mw[r] = mlpw[(quad*4 + r)*16 + lo16];
        unsigned o[4]; split4(mw, o);
        mlpA[0].u[0]=o[0]; mlpA[0].u[1]=o[1]; mlpA[0].u[2]=o[0]; mlpA[0].u[3]=o[1];
        mlpA[1].u[0]=o[2]; mlpA[1].u[1]=o[3]; mlpA[1].u[2]=o[2]; mlpA[1].u[3]=o[3];
    }
    float mlpbr[4];
    #pragma unroll
    for (int r = 0; r < 4; r++) mlpbr[r] = mlpb[quad*4 + r];
    // midw/midb for X0 cols quad*4+j
    float mw0[4], mw1[4], mw2[4], mbv[4];
    #pragma unroll
    for (int j = 0; j < 4; j++){
        int m2 = quad*4 + j;
        mw0[j] = midw[m2]; mw1[j] = midw[16 + m2]; mw2[j] = midw[32 + m2];
        mbv[j] = midb[m2];
    }
    float b2r[4];
    #pragma unroll
    for (int b = 0; b < 4; b++) b2r[b] = b2[b*16 + lo16];
    const float endb0 = endb[lane], endb1 = endb[64 + lane];

    const int wglobal = blockIdx.x*4 + wave;   // 0..4095

    #pragma unroll 1
    for (int it = 0; it < 4; it++){
        const int nr = wglobal*4 + it;

        // ---- issue all global loads up front (latency hidden by h1 VALU) ----
        const int pb = nr*48 + lo16*3;
        float P0 = P[pb], P1 = P[pb+1], P2 = P[pb+2];
        float pp0 = p[nr*3], pp1 = p[nr*3+1], pp2 = p[nr*3+2];
        float fv[4][4];                        // F[nr][quad*4+r][bt*16+lo16]
        #pragma unroll
        for (int bt = 0; bt < 4; bt++)
            #pragma unroll
            for (int r = 0; r < 4; r++)
                fv[bt][r] = F[(size_t)nr*1024 + (quad*4 + r)*64 + bt*16 + lo16];

        const float pn0 = (P0 - pp0)*sc[0] + sh[0];
        const float pn1 = (P1 - pp1)*sc[1] + sh[1];
        const float pn2 = (P2 - pp2)*sc[2] + sh[2];

        // ---- h1 A-frags (lift1 + ELU + bf16 pack), fully in-lane ----
        FragU hf[2];
        #pragma unroll
        for (int s = 0; s < 2; s++)
            #pragma unroll
            for (int d = 0; d < 4; d++){
                float e[2];
                #pragma unroll
                for (int h2 = 0; h2 < 2; h2++){
                    unsigned pa = w1pk[s][2*d + h2][0], pbk = w1pk[s][2*d + h2][1];
                    float h = bf_hi(pbk);
                    h = fmaf(pn0, bf_lo(pa), h);
                    h = fmaf(pn1, bf_hi(pa), h);
                    h = fmaf(pn2, bf_lo(pbk), h);
                    e[h2] = elu_f(h);
                }
                hf[s].u[d] = pk_bf16(e[0], e[1]);
            }

        // ---- X0 (exact fp32) -> split B-frag ----
        float x0[4];
        #pragma unroll
        for (int j = 0; j < 4; j++)
            x0[j] = fmaf(pn2, mw2[j], fmaf(pn1, mw1[j], fmaf(pn0, mw0[j], mbv[j])));
        FragU x0f; split4(x0, x0f.u);

        // ---- mlp: X^T = mlpw^T @ X0^T (exact via hi/lo), ELU, split -> agg A-frags ----
        f32x4 dx = {0.f,0.f,0.f,0.f};
        dx = __builtin_amdgcn_mfma_f32_16x16x32_bf16(mlpA[0].f, x0f.f, dx, 0,0,0);
        dx = __builtin_amdgcn_mfma_f32_16x16x32_bf16(mlpA[1].f, x0f.f, dx, 0,0,0);
        float xv[4];
        #pragma unroll
        for (int r = 0; r < 4; r++) xv[r] = elu_f(dx[r] + mlpbr[r]);
        unsigned xo[4]; split4(xv, xo);
        FragU xA1, xA2;
        xA1.u[0]=xo[0]; xA1.u[1]=xo[1]; xA1.u[2]=xo[0]; xA1.u[3]=xo[1];   // Xhi dup
        xA2.u[0]=xo[2]; xA2.u[1]=xo[3]; xA2.u[2]=xo[2]; xA2.u[3]=xo[3];   // Xlo dup

        float o0 = 0.f, o1 = 0.f;

        // ---- tiles 0..3: lift2 (MFMA) -> ELU -> split B-frag -> agg (MFMA) ----
        #pragma unroll
        for (int b = 0; b < 4; b++){
            f32x4 dl = {0.f,0.f,0.f,0.f};
            dl = __builtin_amdgcn_mfma_f32_16x16x32_bf16(hf[0].f, w2f[b][0].f, dl, 0,0,0);
            dl = __builtin_amdgcn_mfma_f32_16x16x32_bf16(hf[1].f, w2f[b][1].f, dl, 0,0,0);
            float fl[4];
            #pragma unroll
            for (int r = 0; r < 4; r++) fl[r] = elu_f(dl[r] + b2r[b]);
            FragU bfg; split4(fl, bfg.u);
            f32x4 da = {0.f,0.f,0.f,0.f};
            da = __builtin_amdgcn_mfma_f32_16x16x32_bf16(xA1.f, bfg.f, da, 0,0,0);
            da = __builtin_amdgcn_mfma_f32_16x16x32_bf16(xA2.f, bfg.f, da, 0,0,0);
            const float4 ew = *(const float4*)&sEndw[(b*16 + lo16)*20 + quad*4];
            float pt = da[0]*ew.x + da[1]*ew.y + da[2]*ew.z + da[3]*ew.w;
            pt += __shfl_xor(pt, 16, 64);
            pt += __shfl_xor(pt, 32, 64);
            if (b == quad) o0 = pt;            // c = b*16+lo16 == lane
        }
        // ---- tiles 4..7: raw F -> split B-frag -> agg (MFMA) ----
        #pragma unroll
        for (int bt = 0; bt < 4; bt++){
            FragU bfg; split4(fv[bt], bfg.u);
            f32x4 da = {0.f,0.f,0.f,0.f};
            da = __builtin_amdgcn_mfma_f32_16x16x32_bf16(xA1.f, bfg.f, da, 0,0,0);
            da = __builtin_amdgcn_mfma_f32_16x16x32_bf16(xA2.f, bfg.f, da, 0,0,0);
            const float4 ew = *(const float4*)&sEndw[(64 + bt*16 + lo16)*20 + quad*4];
            float pt = da[0]*ew.x + da[1]*ew.y + da[2]*ew.z + da[3]*ew.w;
            pt += __shfl_xor(pt, 16, 64);
            pt += __shfl_xor(pt, 32, 64);
            if (bt == quad) o1 = pt;           // c = 64 + bt*16+lo16 == 64+lane
        }

        out[(size_t)nr*CM + lane]      = o0 + endb0;
        out[(size_t)nr*CM + 64 + lane] = o1 + endb1;
    }
}

extern "C" void kernel_launch(void* const* d_in, const int* in_sizes, int n_in,
                              void* d_out, int out_size, void* d_ws, size_t ws_size,
                              hipStream_t stream)
{
    const float* p     = (const float*)d_in[0];
    const float* P     = (const float*)d_in[1];
    const float* F     = (const float*)d_in[2];
    const float* gamma = (const float*)d_in[3];
    const float* beta  = (const float*)d_in[4];
    const float* w1    = (const float*)d_in[5];
    const float* b1    = (const float*)d_in[6];
    const float* w2    = (const float*)d_in[7];
    const float* b2    = (const float*)d_in[8];
    const float* midw  = (const float*)d_in[9];
    const float* midb  = (const float*)d_in[10];
    const float* mlpw  = (const float*)d_in[11];
    const float* mlpb  = (const float*)d_in[12];
    const float* endw  = (const float*)d_in[13];
    const float* endb  = (const float*)d_in[14];
    float* ws  = (float*)d_ws;
    float* out = (float*)d_out;

    hipMemsetAsync(d_ws, 0, 32, stream);
    xconv_stats<<<256, 256, 0, stream>>>(p, P, ws);
    xconv_main <<<1024, 256, 0, stream>>>(p, P, F, gamma, beta, w1, b1, w2, b2,
                                          midw, midb, mlpw, mlpb, endw, endb, ws, out);
}